// Round 2
// baseline (1008.399 us; speedup 1.0000x reference)
//
#include <hip/hip_runtime.h>
#include <math.h>

#define T_TOK 8192
#define CD 1024
#define HD 4096
#define NE 8
#define MAX_SLOTS 18432   // 16384 + 8*255 pad, rounded up

#define TB 256            // tile M = N
#define TK 64             // K-step
// max m-blocks per expert: ceil(8448/256)=33, padded to multiple of 4 -> 36
#define MB36 36

typedef __bf16 bf16x8 __attribute__((ext_vector_type(8)));
typedef float f32x4 __attribute__((ext_vector_type(4)));

__device__ __forceinline__ unsigned short f2bf(float f) {
  union { float f; unsigned int u; } v; v.f = f;
  unsigned int u = v.u;
  return (unsigned short)((u + 0x7FFFu + ((u >> 16) & 1u)) >> 16);  // RNE
}

__device__ __forceinline__ float gelu_fast(float x) {
  // tanh-form gelu as x * sigmoid(2z)
  float x3 = x * x * x;
  float z = 0.7978845608028654f * (x + 0.044715f * x3);
  float ez = __expf(-2.0f * z);
  return x * __builtin_amdgcn_rcpf(1.0f + ez);
}

__device__ __forceinline__ void glds16(const void* g, void* l) {
  __builtin_amdgcn_global_load_lds((__attribute__((address_space(1))) void*)g,
                                   (__attribute__((address_space(3))) void*)l,
                                   16, 0, 0);
}

// ---------------- router ----------------
__global__ void router_kernel(const float* __restrict__ x, const float* __restrict__ gw,
                              int* __restrict__ meta, int* __restrict__ route_e,
                              float* __restrict__ route_w) {
  __shared__ float4 sgw4[NE * (CD / 4)];  // 32 KB
  __shared__ int hist[NE];
  const int tid = threadIdx.x;
  for (int idx = tid; idx < NE * CD / 4; idx += 256) sgw4[idx] = ((const float4*)gw)[idx];
  if (tid < NE) hist[tid] = 0;
  __syncthreads();
  const int wave = tid >> 6, lane = tid & 63;
  const int t0 = blockIdx.x * 16 + wave * 4;
#pragma unroll
  for (int tt = 0; tt < 4; tt++) {
    const int t = t0 + tt;
    const float4* xr4 = (const float4*)(x + (size_t)t * CD);
    float4 xv[4];
#pragma unroll
    for (int it = 0; it < 4; it++) xv[it] = xr4[it * 64 + lane];
    float acc[NE];
#pragma unroll
    for (int e = 0; e < NE; e++) acc[e] = 0.f;
#pragma unroll
    for (int it = 0; it < 4; it++) {
#pragma unroll
      for (int e = 0; e < NE; e++) {
        float4 g = sgw4[e * 256 + it * 64 + lane];
        acc[e] += xv[it].x * g.x + xv[it].y * g.y + xv[it].z * g.z + xv[it].w * g.w;
      }
    }
#pragma unroll
    for (int e = 0; e < NE; e++) {
      float v = acc[e];
#pragma unroll
      for (int off = 32; off > 0; off >>= 1) v += __shfl_xor(v, off);
      acc[e] = v;
    }
    if (lane == 0) {
      float mx = acc[0];
#pragma unroll
      for (int e = 1; e < NE; e++) mx = fmaxf(mx, acc[e]);
      float p[NE], s = 0.f;
#pragma unroll
      for (int e = 0; e < NE; e++) { p[e] = __expf(acc[e] - mx); s += p[e]; }
      float inv = 1.0f / s;
#pragma unroll
      for (int e = 0; e < NE; e++) p[e] *= inv;
      int i0 = 0;
#pragma unroll
      for (int e = 1; e < NE; e++) if (p[e] > p[i0]) i0 = e;  // strict >: lowest idx on tie
      int i1 = (i0 == 0) ? 1 : 0;
#pragma unroll
      for (int e = 0; e < NE; e++) if (e != i0 && p[e] > p[i1]) i1 = e;
      float den = p[i0] + p[i1] + 1e-8f;
      route_e[t * 2 + 0] = i0; route_e[t * 2 + 1] = i1;
      route_w[t * 2 + 0] = p[i0] / den; route_w[t * 2 + 1] = p[i1] / den;
      atomicAdd(&hist[i0], 1);
      atomicAdd(&hist[i1], 1);
    }
  }
  __syncthreads();
  if (tid < NE && hist[tid] > 0) atomicAdd(&meta[tid], hist[tid]);
}

// meta: [0:8) cnt, [8:16) offs, [16:24) mpad, [24:32) cursor
__global__ void offsets_kernel(int* meta) {
  if (threadIdx.x == 0 && blockIdx.x == 0) {
    int off = 0;
    for (int e = 0; e < NE; e++) {
      int pc = (meta[e] + 255) & ~255;   // pad to 256 rows (= TB)
      meta[8 + e] = off;
      meta[16 + e] = pc;
      off += pc;
    }
  }
}

__global__ void scatter_kernel(const int* __restrict__ route_e, const float* __restrict__ route_w,
                               int* __restrict__ meta, int* __restrict__ slot_token,
                               int* __restrict__ tok_slot) {
  __shared__ int hist[NE], base[NE];
  const int tid = threadIdx.x;
  const int t = blockIdx.x * 256 + tid;
  if (tid < NE) hist[tid] = 0;
  __syncthreads();
  int e0 = route_e[t * 2 + 0], e1 = route_e[t * 2 + 1];
  int lr0 = atomicAdd(&hist[e0], 1);
  int lr1 = atomicAdd(&hist[e1], 1);
  __syncthreads();
  if (tid < NE) base[tid] = (hist[tid] > 0) ? atomicAdd(&meta[24 + tid], hist[tid]) : 0;
  __syncthreads();
  int s0 = meta[8 + e0] + base[e0] + lr0;
  int s1 = meta[8 + e1] + base[e1] + lr1;
  slot_token[s0] = t;
  slot_token[s1] = t;
  tok_slot[t * 2 + 0] = s0;
  tok_slot[t * 2 + 1] = s1;
}

__global__ void gather_kernel(const float* __restrict__ x, const int* __restrict__ slot_token,
                              unsigned short* __restrict__ xg) {
  int slot = blockIdx.x;
  int tkn = slot_token[slot];
  int i = threadIdx.x * 4;
  ushort4 o;
  if (tkn < 0) {
    o.x = 0; o.y = 0; o.z = 0; o.w = 0;
  } else {
    const float4 v = *(const float4*)(x + (size_t)tkn * CD + i);
    o.x = f2bf(v.x); o.y = f2bf(v.y); o.z = f2bf(v.z); o.w = f2bf(v.w);
  }
  *(ushort4*)(xg + (size_t)slot * CD + i) = o;
}

// convert both weight tensors in one launch (each NE*HD*CD floats)
__global__ void cvtw_kernel(const float* __restrict__ w1, const float* __restrict__ w2,
                            unsigned short* __restrict__ d1, unsigned short* __restrict__ d2) {
  const int n4 = NE * HD * CD / 4;
  int i = blockIdx.x * 256 + threadIdx.x;
  const float* s; unsigned short* d;
  if (i < n4) { s = w1; d = d1; }
  else        { s = w2; d = d2; i -= n4; }
  const float4 v = *(const float4*)(s + (size_t)i * 4);
  ushort4 o;
  o.x = f2bf(v.x); o.y = f2bf(v.y); o.z = f2bf(v.z); o.w = f2bf(v.w);
  *(ushort4*)(d + (size_t)i * 4) = o;
}

// ======================= GEMM1: h = gelu(x_g @ w1^T + b1), K=CD =======================
// 256x256 tile, BK=64, 512 threads (8 waves: 2 wm x 4 wn, per-wave 128x64 C).
// Double-buffered 128 KB LDS, 4-phase (quadrant) pipelined schedule: phases 0-1 of tile t
// issue all 8 global_load_lds for tile t+1 (>=2 phases of MFMA cover), one barrier per
// phase, single vmcnt drain at the tile boundary only. setprio(1) around MFMA cluster.
// XOR-swizzled 16B granules (inverse-swizzled global source, swizzled LDS read).
__global__ __launch_bounds__(512, 2)
void gemm1_kernel(const unsigned short* __restrict__ Ag,   // x_g [MAX_SLOTS][CD]
                  const unsigned short* __restrict__ W1,   // bf16 w1 [NE][HD][CD]
                  const float* __restrict__ b1,            // [NE][HD]
                  unsigned short* __restrict__ Hout,       // h [MAX_SLOTS][HD]
                  const int* __restrict__ meta) {
  const int gid = blockIdx.x;
  const int e = gid & 7;
  const int rr = gid >> 3;                 // [0, 576): 36 m x 16 n
  const int mi = rr & 3, ni = (rr >> 2) & 3;
  const int sup = rr >> 4;                 // [0,36): 9 msup x 4 nsup, msup fastest
  const int msup = sup % 9, nsup = sup / 9;
  const int m_idx = msup * 4 + mi;
  const int n_idx = nsup * 4 + ni;
  const int mpad = meta[16 + e];
  const int m0 = m_idx * TB;
  if (m0 >= mpad) return;
  const int n0 = n_idx * TB;
  const int off = meta[8 + e];
  const unsigned short* A = Ag + (size_t)(off + m0) * CD;
  const unsigned short* B = W1 + (size_t)e * (HD * CD) + (size_t)n0 * CD;
  const float* bias = b1 + (size_t)e * HD;

  __shared__ unsigned short As[2][TB * TK];  // 2 x 32 KB
  __shared__ unsigned short Bs[2][TB * TK];  // 2 x 32 KB

  const int tid = threadIdx.x;
  const int lane = tid & 63, wave = tid >> 6;
  const int wm = wave >> 2, wn = wave & 3;
  const int r = lane & 15, qq = lane >> 4, rx = r & 7;
  const int lr = lane >> 3, lc = lane & 7;
  const int gc = lc ^ lr;                    // inverse-swizzled source granule

  // staging: issue c covers rows c*64 + wave*8 + [0,8); linear LDS dest, swizzled src
  const unsigned short* pA[4]; const unsigned short* pB[4]; int dOff[4];
#pragma unroll
  for (int c = 0; c < 4; c++) {
    const int row = c * 64 + wave * 8 + lr;
    pA[c] = A + (size_t)row * CD + gc * 8;
    pB[c] = B + (size_t)row * CD + gc * 8;
    dOff[c] = (c * 64 + wave * 8) * TK;
  }
  const int aBase = (wm * 128 + r) * TK;
  const int bBase = (wn * 64 + r) * TK;
  const int g0 = (qq ^ rx) << 3;
  const int g1 = ((4 | qq) ^ rx) << 3;

  f32x4 acc[8][4];
#pragma unroll
  for (int i = 0; i < 8; i++)
#pragma unroll
    for (int j = 0; j < 4; j++) acc[i][j] = 0.f;

  // prologue: stage tile 0 into buffer 0
#pragma unroll
  for (int c = 0; c < 4; c++) glds16(pA[c], &As[0][dOff[c]]);
#pragma unroll
  for (int c = 0; c < 4; c++) glds16(pB[c], &Bs[0][dOff[c]]);
  asm volatile("s_waitcnt vmcnt(0)" ::: "memory");
  __syncthreads();

  const int NKT = CD / TK;   // 16
  for (int kt = 0; kt < NKT; kt++) {
    const int cur = kt & 1;
    const unsigned short* Ab = &As[cur][0];
    const unsigned short* Bb = &Bs[cur][0];
    unsigned short* AsN = &As[cur ^ 1][0];
    unsigned short* BsN = &Bs[cur ^ 1][0];
    const bool pf = (kt + 1 < NKT);
    const size_t ko = (size_t)(kt + 1) * TK;
#pragma unroll
    for (int q = 0; q < 4; q++) {
      if (pf) {  // front-load staging: phases 0-1 issue everything for tile kt+1
        if (q == 0) {
          glds16(pA[0] + ko, AsN + dOff[0]); glds16(pA[1] + ko, AsN + dOff[1]);
          glds16(pA[2] + ko, AsN + dOff[2]); glds16(pA[3] + ko, AsN + dOff[3]);
        } else if (q == 1) {
          glds16(pB[0] + ko, BsN + dOff[0]); glds16(pB[1] + ko, BsN + dOff[1]);
          glds16(pB[2] + ko, BsN + dOff[2]); glds16(pB[3] + ko, BsN + dOff[3]);
        }
      }
      const int qm = q >> 1, qn = q & 1;
      bf16x8 af[4][2], bq[2][2];
#pragma unroll
      for (int i = 0; i < 4; i++) {
        af[i][0] = *(const bf16x8*)&Ab[aBase + (qm * 4 + i) * (16 * TK) + g0];
        af[i][1] = *(const bf16x8*)&Ab[aBase + (qm * 4 + i) * (16 * TK) + g1];
      }
#pragma unroll
      for (int j = 0; j < 2; j++) {
        bq[j][0] = *(const bf16x8*)&Bb[bBase + (qn * 2 + j) * (16 * TK) + g0];
        bq[j][1] = *(const bf16x8*)&Bb[bBase + (qn * 2 + j) * (16 * TK) + g1];
      }
      __builtin_amdgcn_s_setprio(1);
#pragma unroll
      for (int i = 0; i < 4; i++)
#pragma unroll
        for (int j = 0; j < 2; j++) {
          acc[qm * 4 + i][qn * 2 + j] = __builtin_amdgcn_mfma_f32_16x16x32_bf16(
              af[i][0], bq[j][0], acc[qm * 4 + i][qn * 2 + j], 0, 0, 0);
          acc[qm * 4 + i][qn * 2 + j] = __builtin_amdgcn_mfma_f32_16x16x32_bf16(
              af[i][1], bq[j][1], acc[qm * 4 + i][qn * 2 + j], 0, 0, 0);
        }
      __builtin_amdgcn_s_setprio(0);
      if (q == 3) asm volatile("s_waitcnt vmcnt(0)" ::: "memory");  // publish tile kt+1
      __syncthreads();
    }
  }
  // epilogue: C/D col = lane&15 (-> n), row = quad*4 + reg (-> m)
  const int orow0 = off + m0 + wm * 128 + qq * 4;
#pragma unroll
  for (int j = 0; j < 4; j++) {
    const int n = n0 + wn * 64 + j * 16 + r;
    const float bj = bias[n];
#pragma unroll
    for (int i = 0; i < 8; i++) {
#pragma unroll
      for (int g = 0; g < 4; g++) {
        const int row = orow0 + i * 16 + g;
        Hout[(size_t)row * HD + n] = f2bf(gelu_fast(acc[i][j][g] + bj));
      }
    }
  }
}

// ========== GEMM2: Y[slot] = h @ w2^T + b2, K=HD. Same pipelined 256^2 structure. ==========
__global__ __launch_bounds__(512, 2)
void gemm2_kernel(const unsigned short* __restrict__ Hin,  // h [MAX_SLOTS][HD]
                  const unsigned short* __restrict__ W2,   // bf16 w2 [NE][CD][HD]
                  const float* __restrict__ b2,            // [NE][CD]
                  const int* __restrict__ meta,
                  float* __restrict__ Y) {                 // [MAX_SLOTS][CD] f32
  const int gid = blockIdx.x;
  const int e = gid & 7;
  const int rr = gid >> 3;                 // [0, 144): 36 m x 4 n
  const int mi = rr & 3, ni = (rr >> 2) & 3;
  const int sup = rr >> 4;                 // [0,9): msup only (all 4 n in supertile)
  const int m_idx = sup * 4 + mi;
  const int n_idx = ni;
  const int mpad = meta[16 + e];
  const int m0 = m_idx * TB;
  if (m0 >= mpad) return;
  const int n0 = n_idx * TB;
  const int off = meta[8 + e];
  const unsigned short* A = Hin + (size_t)(off + m0) * HD;
  const unsigned short* B = W2 + (size_t)e * (CD * HD) + (size_t)n0 * HD;
  const float* bias = b2 + (size_t)e * CD;

  __shared__ unsigned short As[2][TB * TK];
  __shared__ unsigned short Bs[2][TB * TK];

  const int tid = threadIdx.x;
  const int lane = tid & 63, wave = tid >> 6;
  const int wm = wave >> 2, wn = wave & 3;
  const int r = lane & 15, qq = lane >> 4, rx = r & 7;
  const int lr = lane >> 3, lc = lane & 7;
  const int gc = lc ^ lr;

  const unsigned short* pA[4]; const unsigned short* pB[4]; int dOff[4];
#pragma unroll
  for (int c = 0; c < 4; c++) {
    const int row = c * 64 + wave * 8 + lr;
    pA[c] = A + (size_t)row * HD + gc * 8;
    pB[c] = B + (size_t)row * HD + gc * 8;
    dOff[c] = (c * 64 + wave * 8) * TK;
  }
  const int aBase = (wm * 128 + r) * TK;
  const int bBase = (wn * 64 + r) * TK;
  const int g0 = (qq ^ rx) << 3;
  const int g1 = ((4 | qq) ^ rx) << 3;

  f32x4 acc[8][4];
#pragma unroll
  for (int i = 0; i < 8; i++)
#pragma unroll
    for (int j = 0; j < 4; j++) acc[i][j] = 0.f;

#pragma unroll
  for (int c = 0; c < 4; c++) glds16(pA[c], &As[0][dOff[c]]);
#pragma unroll
  for (int c = 0; c < 4; c++) glds16(pB[c], &Bs[0][dOff[c]]);
  asm volatile("s_waitcnt vmcnt(0)" ::: "memory");
  __syncthreads();

  const int NKT = HD / TK;   // 64
  for (int kt = 0; kt < NKT; kt++) {
    const int cur = kt & 1;
    const unsigned short* Ab = &As[cur][0];
    const unsigned short* Bb = &Bs[cur][0];
    unsigned short* AsN = &As[cur ^ 1][0];
    unsigned short* BsN = &Bs[cur ^ 1][0];
    const bool pf = (kt + 1 < NKT);
    const size_t ko = (size_t)(kt + 1) * TK;
#pragma unroll
    for (int q = 0; q < 4; q++) {
      if (pf) {
        if (q == 0) {
          glds16(pA[0] + ko, AsN + dOff[0]); glds16(pA[1] + ko, AsN + dOff[1]);
          glds16(pA[2] + ko, AsN + dOff[2]); glds16(pA[3] + ko, AsN + dOff[3]);
        } else if (q == 1) {
          glds16(pB[0] + ko, BsN + dOff[0]); glds16(pB[1] + ko, BsN + dOff[1]);
          glds16(pB[2] + ko, BsN + dOff[2]); glds16(pB[3] + ko, BsN + dOff[3]);
        }
      }
      const int qm = q >> 1, qn = q & 1;
      bf16x8 af[4][2], bq[2][2];
#pragma unroll
      for (int i = 0; i < 4; i++) {
        af[i][0] = *(const bf16x8*)&Ab[aBase + (qm * 4 + i) * (16 * TK) + g0];
        af[i][1] = *(const bf16x8*)&Ab[aBase + (qm * 4 + i) * (16 * TK) + g1];
      }
#pragma unroll
      for (int j = 0; j < 2; j++) {
        bq[j][0] = *(const bf16x8*)&Bb[bBase + (qn * 2 + j) * (16 * TK) + g0];
        bq[j][1] = *(const bf16x8*)&Bb[bBase + (qn * 2 + j) * (16 * TK) + g1];
      }
      __builtin_amdgcn_s_setprio(1);
#pragma unroll
      for (int i = 0; i < 4; i++)
#pragma unroll
        for (int j = 0; j < 2; j++) {
          acc[qm * 4 + i][qn * 2 + j] = __builtin_amdgcn_mfma_f32_16x16x32_bf16(
              af[i][0], bq[j][0], acc[qm * 4 + i][qn * 2 + j], 0, 0, 0);
          acc[qm * 4 + i][qn * 2 + j] = __builtin_amdgcn_mfma_f32_16x16x32_bf16(
              af[i][1], bq[j][1], acc[qm * 4 + i][qn * 2 + j], 0, 0, 0);
        }
      __builtin_amdgcn_s_setprio(0);
      if (q == 3) asm volatile("s_waitcnt vmcnt(0)" ::: "memory");
      __syncthreads();
    }
  }
  const int orow0 = off + m0 + wm * 128 + qq * 4;
#pragma unroll
  for (int j = 0; j < 4; j++) {
    const int n = n0 + wn * 64 + j * 16 + r;
    const float bj = bias[n];
#pragma unroll
    for (int i = 0; i < 8; i++) {
#pragma unroll
      for (int g = 0; g < 4; g++) {
        const int row = orow0 + i * 16 + g;
        Y[(size_t)row * CD + n] = acc[i][j][g] + bj;
      }
    }
  }
}

// out[t] = w0 * Y[s0] + w1 * Y[s1]  (each Y row already includes its expert's bias)
__global__ void combine_kernel(const float* __restrict__ Y, const int* __restrict__ tok_slot,
                               const float* __restrict__ route_w, float* __restrict__ out) {
  const int t = blockIdx.x;
  const int i = threadIdx.x;
  const int s0 = tok_slot[t * 2 + 0], s1 = tok_slot[t * 2 + 1];
  const float w0 = route_w[t * 2 + 0], w1v = route_w[t * 2 + 1];
  const float4 a = ((const float4*)(Y + (size_t)s0 * CD))[i];
  const float4 b = ((const float4*)(Y + (size_t)s1 * CD))[i];
  float4 o;
  o.x = w0 * a.x + w1v * b.x;
  o.y = w0 * a.y + w1v * b.y;
  o.z = w0 * a.z + w1v * b.z;
  o.w = w0 * a.w + w1v * b.w;
  ((float4*)(out + (size_t)t * CD))[i] = o;
}

extern "C" void kernel_launch(void* const* d_in, const int* in_sizes, int n_in,
                              void* d_out, int out_size, void* d_ws, size_t ws_size,
                              hipStream_t stream) {
  const float* x  = (const float*)d_in[0];
  const float* gw = (const float*)d_in[1];
  const float* w1 = (const float*)d_in[2];
  const float* b1 = (const float*)d_in[3];
  const float* w2 = (const float*)d_in[4];
  const float* b2 = (const float*)d_in[5];
  float* out = (float*)d_out;

  char* p = (char*)d_ws;
  size_t o = 0;
  int* meta = (int*)p;                   o = 256;
  int* slot_token = (int*)(p + o);       o += (size_t)MAX_SLOTS * 4;
  int* tok_slot = (int*)(p + o);         o += (size_t)T_TOK * 8;
  int* route_e = (int*)(p + o);          o += (size_t)T_TOK * 8;
  float* route_w = (float*)(p + o);      o += (size_t)T_TOK * 8;
  o = (o + 255) & ~(size_t)255;
  unsigned short* xg  = (unsigned short*)(p + o); o += (size_t)MAX_SLOTS * CD * 2;
  unsigned short* w1b = (unsigned short*)(p + o); o += (size_t)NE * HD * CD * 2;
  unsigned short* w2b = (unsigned short*)(p + o); o += (size_t)NE * CD * HD * 2;
  unsigned short* h   = (unsigned short*)(p + o); o += (size_t)MAX_SLOTS * HD * 2;
  if (ws_size < o) return;  // fail cleanly if workspace too small
  // Y (75.5 MB f32) aliases [xg, w1b) (104.8 MB): both are dead once gemm1 completes,
  // and gemm2/combine run strictly after gemm1 on this stream.
  float* Y = (float*)xg;

  hipMemsetAsync(meta, 0, 256, stream);
  hipMemsetAsync(slot_token, 0xFF, (size_t)MAX_SLOTS * 4, stream);  // -1

  router_kernel<<<T_TOK / 16, 256, 0, stream>>>(x, gw, meta, route_e, route_w);
  offsets_kernel<<<1, 64, 0, stream>>>(meta);
  scatter_kernel<<<T_TOK / 256, 256, 0, stream>>>(route_e, route_w, meta, slot_token, tok_slot);
  gather_kernel<<<MAX_SLOTS, 256, 0, stream>>>(x, slot_token, xg);

  const int n4w = NE * HD * CD / 4;
  cvtw_kernel<<<2 * n4w / 256, 256, 0, stream>>>(w1, w2, w1b, w2b);

  // gemm1: 8 experts x (36 m x 16 n); gemm2: 8 x (36 m x 4 n); inactive m-blocks early-return
  gemm1_kernel<<<NE * MB36 * 16, 512, 0, stream>>>(xg, w1b, b1, h, meta);
  gemm2_kernel<<<NE * MB36 * 4, 512, 0, stream>>>(h, w2b, b2, meta, Y);
  combine_kernel<<<T_TOK, 256, 0, stream>>>(Y, tok_slot, route_w, out);
}

// Round 3
// 986.449 us; speedup vs baseline: 1.0223x; 1.0223x over previous
//
#include <hip/hip_runtime.h>
#include <math.h>

#define T_TOK 8192
#define CD 1024
#define HD 4096
#define NE 8
#define MAX_SLOTS 18432   // 16384 + 8*255 pad, rounded up

#define BM 256            // tile M
#define BN 128            // tile N
#define TK 64             // K-step
#define MB36 36           // max m-blocks per expert, padded to /4 for supertiles

typedef __bf16 bf16x8 __attribute__((ext_vector_type(8)));
typedef float f32x4 __attribute__((ext_vector_type(4)));

__device__ __forceinline__ unsigned short f2bf(float f) {
  union { float f; unsigned int u; } v; v.f = f;
  unsigned int u = v.u;
  return (unsigned short)((u + 0x7FFFu + ((u >> 16) & 1u)) >> 16);  // RNE
}

__device__ __forceinline__ float gelu_fast(float x) {
  float x3 = x * x * x;
  float z = 0.7978845608028654f * (x + 0.044715f * x3);
  float ez = __expf(-2.0f * z);
  return x * __builtin_amdgcn_rcpf(1.0f + ez);
}

__device__ __forceinline__ void glds16(const void* g, void* l) {
  __builtin_amdgcn_global_load_lds((__attribute__((address_space(1))) void*)g,
                                   (__attribute__((address_space(3))) void*)l,
                                   16, 0, 0);
}

// ---------------- router ----------------
__global__ void router_kernel(const float* __restrict__ x, const float* __restrict__ gw,
                              int* __restrict__ meta, int* __restrict__ route_e,
                              float* __restrict__ route_w) {
  __shared__ float4 sgw4[NE * (CD / 4)];  // 32 KB
  __shared__ int hist[NE];
  const int tid = threadIdx.x;
  for (int idx = tid; idx < NE * CD / 4; idx += 256) sgw4[idx] = ((const float4*)gw)[idx];
  if (tid < NE) hist[tid] = 0;
  __syncthreads();
  const int wave = tid >> 6, lane = tid & 63;
  const int t0 = blockIdx.x * 16 + wave * 4;
#pragma unroll
  for (int tt = 0; tt < 4; tt++) {
    const int t = t0 + tt;
    const float4* xr4 = (const float4*)(x + (size_t)t * CD);
    float4 xv[4];
#pragma unroll
    for (int it = 0; it < 4; it++) xv[it] = xr4[it * 64 + lane];
    float acc[NE];
#pragma unroll
    for (int e = 0; e < NE; e++) acc[e] = 0.f;
#pragma unroll
    for (int it = 0; it < 4; it++) {
#pragma unroll
      for (int e = 0; e < NE; e++) {
        float4 g = sgw4[e * 256 + it * 64 + lane];
        acc[e] += xv[it].x * g.x + xv[it].y * g.y + xv[it].z * g.z + xv[it].w * g.w;
      }
    }
#pragma unroll
    for (int e = 0; e < NE; e++) {
      float v = acc[e];
#pragma unroll
      for (int off = 32; off > 0; off >>= 1) v += __shfl_xor(v, off);
      acc[e] = v;
    }
    if (lane == 0) {
      float mx = acc[0];
#pragma unroll
      for (int e = 1; e < NE; e++) mx = fmaxf(mx, acc[e]);
      float p[NE], s = 0.f;
#pragma unroll
      for (int e = 0; e < NE; e++) { p[e] = __expf(acc[e] - mx); s += p[e]; }
      float inv = 1.0f / s;
#pragma unroll
      for (int e = 0; e < NE; e++) p[e] *= inv;
      int i0 = 0;
#pragma unroll
      for (int e = 1; e < NE; e++) if (p[e] > p[i0]) i0 = e;  // strict >: lowest idx on tie
      int i1 = (i0 == 0) ? 1 : 0;
#pragma unroll
      for (int e = 0; e < NE; e++) if (e != i0 && p[e] > p[i1]) i1 = e;
      float den = p[i0] + p[i1] + 1e-8f;
      route_e[t * 2 + 0] = i0; route_e[t * 2 + 1] = i1;
      route_w[t * 2 + 0] = p[i0] / den; route_w[t * 2 + 1] = p[i1] / den;
      atomicAdd(&hist[i0], 1);
      atomicAdd(&hist[i1], 1);
    }
  }
  __syncthreads();
  if (tid < NE && hist[tid] > 0) atomicAdd(&meta[tid], hist[tid]);
}

// meta: [0:8) cnt, [8:16) offs, [16:24) mpad, [24:32) cursor
__global__ void offsets_kernel(int* meta) {
  if (threadIdx.x == 0 && blockIdx.x == 0) {
    int off = 0;
    for (int e = 0; e < NE; e++) {
      int pc = (meta[e] + 255) & ~255;   // pad to 256 rows (= BM)
      meta[8 + e] = off;
      meta[16 + e] = pc;
      off += pc;
    }
  }
}

__global__ void scatter_kernel(const int* __restrict__ route_e, const float* __restrict__ route_w,
                               int* __restrict__ meta, int* __restrict__ slot_token,
                               int* __restrict__ tok_slot) {
  __shared__ int hist[NE], base[NE];
  const int tid = threadIdx.x;
  const int t = blockIdx.x * 256 + tid;
  if (tid < NE) hist[tid] = 0;
  __syncthreads();
  int e0 = route_e[t * 2 + 0], e1 = route_e[t * 2 + 1];
  int lr0 = atomicAdd(&hist[e0], 1);
  int lr1 = atomicAdd(&hist[e1], 1);
  __syncthreads();
  if (tid < NE) base[tid] = (hist[tid] > 0) ? atomicAdd(&meta[24 + tid], hist[tid]) : 0;
  __syncthreads();
  int s0 = meta[8 + e0] + base[e0] + lr0;
  int s1 = meta[8 + e1] + base[e1] + lr1;
  slot_token[s0] = t;
  slot_token[s1] = t;
  tok_slot[t * 2 + 0] = s0;
  tok_slot[t * 2 + 1] = s1;
}

__global__ void gather_kernel(const float* __restrict__ x, const int* __restrict__ slot_token,
                              unsigned short* __restrict__ xg) {
  int slot = blockIdx.x;
  int tkn = slot_token[slot];
  int i = threadIdx.x * 4;
  ushort4 o;
  if (tkn < 0) {
    o.x = 0; o.y = 0; o.z = 0; o.w = 0;
  } else {
    const float4 v = *(const float4*)(x + (size_t)tkn * CD + i);
    o.x = f2bf(v.x); o.y = f2bf(v.y); o.z = f2bf(v.z); o.w = f2bf(v.w);
  }
  *(ushort4*)(xg + (size_t)slot * CD + i) = o;
}

// convert both weight tensors in one launch (each NE*HD*CD floats)
__global__ void cvtw_kernel(const float* __restrict__ w1, const float* __restrict__ w2,
                            unsigned short* __restrict__ d1, unsigned short* __restrict__ d2) {
  const int n4 = NE * HD * CD / 4;
  int i = blockIdx.x * 256 + threadIdx.x;
  const float* s; unsigned short* d;
  if (i < n4) { s = w1; d = d1; }
  else        { s = w2; d = d2; i -= n4; }
  const float4 v = *(const float4*)(s + (size_t)i * 4);
  ushort4 o;
  o.x = f2bf(v.x); o.y = f2bf(v.y); o.z = f2bf(v.z); o.w = f2bf(v.w);
  *(ushort4*)(d + (size_t)i * 4) = o;
}

// ======================= GEMM1: h = gelu(x_g @ w1^T + b1), K=CD =======================
// 256x128 tile, TK=64, 512 threads (8 waves: 4 wm x 2 wn, per-wave 64x64 C).
// TRIPLE-buffered LDS (144 KB): during tile t, stage tile t+2; tile-end wait is a
// COUNTED s_waitcnt vmcnt(6) (t+2's 6 loads stay in flight) + ONE raw s_barrier per
// tile (no __syncthreads -> no compiler vmcnt(0) drain). setprio around MFMA cluster.
// XOR-swizzled 16B granules (inverse-swizzled global source, swizzled LDS read).
__global__ __launch_bounds__(512, 1)
void gemm1_kernel(const unsigned short* __restrict__ Ag,   // x_g [MAX_SLOTS][CD]
                  const unsigned short* __restrict__ W1,   // bf16 w1 [NE][HD][CD]
                  const float* __restrict__ b1,            // [NE][HD]
                  unsigned short* __restrict__ Hout,       // h [MAX_SLOTS][HD]
                  const int* __restrict__ meta) {
  const int gid = blockIdx.x;
  const int e = gid & 7;                   // expert -> XCD pin
  const int rr = gid >> 3;                 // [0, 1152): 36 m x 32 n
  const int mi = rr & 3, ni = (rr >> 2) & 3;
  const int sup = rr >> 4;                 // [0,72): 9 msup x 8 nsup
  const int msup = sup % 9, nsup = sup / 9;
  const int m_idx = msup * 4 + mi;         // [0,36)
  const int n_idx = nsup * 4 + ni;         // [0,32)
  const int mpad = meta[16 + e];
  const int m0 = m_idx * BM;
  if (m0 >= mpad) return;
  const int n0 = n_idx * BN;
  const int off = meta[8 + e];
  const unsigned short* A = Ag + (size_t)(off + m0) * CD;
  const unsigned short* B = W1 + (size_t)e * (HD * CD) + (size_t)n0 * CD;
  const float* bias = b1 + (size_t)e * HD;

  __shared__ unsigned short As[3][BM * TK];  // 3 x 32 KB
  __shared__ unsigned short Bs[3][BN * TK];  // 3 x 16 KB

  const int tid = threadIdx.x;
  const int lane = tid & 63, wave = tid >> 6;
  const int wm = wave >> 1, wn = wave & 1;   // wm [0,4) -> A 64-row blk; wn [0,2) -> B 64-col blk
  const int r = lane & 15, qq = lane >> 4, rx = r & 7;
  const int lr = lane >> 3, lc = lane & 7;
  const int gc = lc ^ lr;                    // inverse-swizzled source granule

  // staging: 6 glds16 per K-tile (A: 4 x 64 rows, B: 2 x 64 rows); per-call 8 KB.
  const unsigned short* pA[4]; int dA[4];
#pragma unroll
  for (int c = 0; c < 4; c++) {
    const int row = c * 64 + wave * 8 + lr;
    pA[c] = A + (size_t)row * CD + gc * 8;
    dA[c] = (c * 64 + wave * 8) * TK;        // wave-uniform LDS dest base
  }
  const unsigned short* pB[2]; int dB[2];
#pragma unroll
  for (int c = 0; c < 2; c++) {
    const int row = c * 64 + wave * 8 + lr;
    pB[c] = B + (size_t)row * CD + gc * 8;
    dB[c] = (c * 64 + wave * 8) * TK;
  }

  f32x4 acc[4][4];
#pragma unroll
  for (int i = 0; i < 4; i++)
#pragma unroll
    for (int j = 0; j < 4; j++) acc[i][j] = 0.f;

  // prologue: stage tile0 -> buf0, tile1 -> buf1 (12 loads), wait tile0 (vmcnt(6))
#pragma unroll
  for (int c = 0; c < 4; c++) glds16(pA[c], &As[0][dA[c]]);
#pragma unroll
  for (int c = 0; c < 2; c++) glds16(pB[c], &Bs[0][dB[c]]);
#pragma unroll
  for (int c = 0; c < 4; c++) glds16(pA[c] + TK, &As[1][dA[c]]);
#pragma unroll
  for (int c = 0; c < 2; c++) glds16(pB[c] + TK, &Bs[1][dB[c]]);
  asm volatile("s_waitcnt vmcnt(6)" ::: "memory");
  __builtin_amdgcn_s_barrier();
  asm volatile("" ::: "memory");
  __builtin_amdgcn_sched_barrier(0);

  const int NKT = CD / TK;   // 16
  int cur = 0;
  for (int t = 0; t < NKT; t++) {
    const int n2 = (cur >= 1) ? cur - 1 : 2;     // (t+2) % 3
    const unsigned short* Ab = &As[cur][0];
    const unsigned short* Bb = &Bs[cur][0];
    unsigned short* An = &As[n2][0];
    unsigned short* Bn = &Bs[n2][0];
    const bool pf = (t + 2 < NKT);
    const size_t ko = (size_t)(t + 2) * TK;
#pragma unroll
    for (int s = 0; s < 2; s++) {
      if (pf) {  // 3 glds per phase for tile t+2
        if (s == 0) {
          glds16(pA[0] + ko, An + dA[0]);
          glds16(pA[1] + ko, An + dA[1]);
          glds16(pB[0] + ko, Bn + dB[0]);
        } else {
          glds16(pA[2] + ko, An + dA[2]);
          glds16(pA[3] + ko, An + dA[3]);
          glds16(pB[1] + ko, Bn + dB[1]);
        }
      }
      const int go = (((s << 2) | qq) ^ rx) << 3;
      bf16x8 af[4], bf[4];
#pragma unroll
      for (int i = 0; i < 4; i++)
        af[i] = *(const bf16x8*)&Ab[(wm * 64 + i * 16 + r) * TK + go];
#pragma unroll
      for (int j = 0; j < 4; j++)
        bf[j] = *(const bf16x8*)&Bb[(wn * 64 + j * 16 + r) * TK + go];
      __builtin_amdgcn_s_setprio(1);
#pragma unroll
      for (int i = 0; i < 4; i++)
#pragma unroll
        for (int j = 0; j < 4; j++)
          acc[i][j] = __builtin_amdgcn_mfma_f32_16x16x32_bf16(af[i], bf[j], acc[i][j], 0, 0, 0);
      __builtin_amdgcn_s_setprio(0);
    }
    if (t < NKT - 1) {
      if (pf) asm volatile("s_waitcnt vmcnt(6)" ::: "memory");  // t+1 resident, t+2 in flight
      else    asm volatile("s_waitcnt vmcnt(0)" ::: "memory");  // tail
      __builtin_amdgcn_s_barrier();
      asm volatile("" ::: "memory");
      __builtin_amdgcn_sched_barrier(0);
    }
    cur = (cur == 2) ? 0 : cur + 1;
  }
  // epilogue: C/D col = lane&15 (-> n), row = quad*4 + reg (-> m)
  const int orow0 = off + m0 + wm * 64 + qq * 4;
#pragma unroll
  for (int j = 0; j < 4; j++) {
    const int n = n0 + wn * 64 + j * 16 + r;
    const float bj = bias[n];
#pragma unroll
    for (int i = 0; i < 4; i++) {
#pragma unroll
      for (int g = 0; g < 4; g++) {
        const int row = orow0 + i * 16 + g;
        Hout[(size_t)row * HD + n] = f2bf(gelu_fast(acc[i][j][g] + bj));
      }
    }
  }
}

// ========== GEMM2: Y[slot] = h @ w2^T + b2, K=HD. Same pipelined structure. ==========
__global__ __launch_bounds__(512, 1)
void gemm2_kernel(const unsigned short* __restrict__ Hin,  // h [MAX_SLOTS][HD]
                  const unsigned short* __restrict__ W2,   // bf16 w2 [NE][CD][HD]
                  const float* __restrict__ b2,            // [NE][CD]
                  const int* __restrict__ meta,
                  float* __restrict__ Y) {                 // [MAX_SLOTS][CD] f32
  const int gid = blockIdx.x;
  const int e = gid & 7;
  const int rr = gid >> 3;                 // [0, 288): 36 m x 8 n
  const int mi = rr & 3, ni = (rr >> 2) & 3;
  const int sup = rr >> 4;                 // [0,18): 9 msup x 2 nsup
  const int msup = sup % 9, nsup = sup / 9;
  const int m_idx = msup * 4 + mi;         // [0,36)
  const int n_idx = nsup * 4 + ni;         // [0,8)
  const int mpad = meta[16 + e];
  const int m0 = m_idx * BM;
  if (m0 >= mpad) return;
  const int n0 = n_idx * BN;
  const int off = meta[8 + e];
  const unsigned short* A = Hin + (size_t)(off + m0) * HD;
  const unsigned short* B = W2 + (size_t)e * (CD * HD) + (size_t)n0 * HD;
  const float* bias = b2 + (size_t)e * CD;

  __shared__ unsigned short As[3][BM * TK];
  __shared__ unsigned short Bs[3][BN * TK];

  const int tid = threadIdx.x;
  const int lane = tid & 63, wave = tid >> 6;
  const int wm = wave >> 1, wn = wave & 1;
  const int r = lane & 15, qq = lane >> 4, rx = r & 7;
  const int lr = lane >> 3, lc = lane & 7;
  const int gc = lc ^ lr;

  const unsigned short* pA[4]; int dA[4];
#pragma unroll
  for (int c = 0; c < 4; c++) {
    const int row = c * 64 + wave * 8 + lr;
    pA[c] = A + (size_t)row * HD + gc * 8;
    dA[c] = (c * 64 + wave * 8) * TK;
  }
  const unsigned short* pB[2]; int dB[2];
#pragma unroll
  for (int c = 0; c < 2; c++) {
    const int row = c * 64 + wave * 8 + lr;
    pB[c] = B + (size_t)row * HD + gc * 8;
    dB[c] = (c * 64 + wave * 8) * TK;
  }

  f32x4 acc[4][4];
#pragma unroll
  for (int i = 0; i < 4; i++)
#pragma unroll
    for (int j = 0; j < 4; j++) acc[i][j] = 0.f;

#pragma unroll
  for (int c = 0; c < 4; c++) glds16(pA[c], &As[0][dA[c]]);
#pragma unroll
  for (int c = 0; c < 2; c++) glds16(pB[c], &Bs[0][dB[c]]);
#pragma unroll
  for (int c = 0; c < 4; c++) glds16(pA[c] + TK, &As[1][dA[c]]);
#pragma unroll
  for (int c = 0; c < 2; c++) glds16(pB[c] + TK, &Bs[1][dB[c]]);
  asm volatile("s_waitcnt vmcnt(6)" ::: "memory");
  __builtin_amdgcn_s_barrier();
  asm volatile("" ::: "memory");
  __builtin_amdgcn_sched_barrier(0);

  const int NKT = HD / TK;   // 64
  int cur = 0;
  for (int t = 0; t < NKT; t++) {
    const int n2 = (cur >= 1) ? cur - 1 : 2;
    const unsigned short* Ab = &As[cur][0];
    const unsigned short* Bb = &Bs[cur][0];
    unsigned short* An = &As[n2][0];
    unsigned short* Bn = &Bs[n2][0];
    const bool pf = (t + 2 < NKT);
    const size_t ko = (size_t)(t + 2) * TK;
#pragma unroll
    for (int s = 0; s < 2; s++) {
      if (pf) {
        if (s == 0) {
          glds16(pA[0] + ko, An + dA[0]);
          glds16(pA[1] + ko, An + dA[1]);
          glds16(pB[0] + ko, Bn + dB[0]);
        } else {
          glds16(pA[2] + ko, An + dA[2]);
          glds16(pA[3] + ko, An + dA[3]);
          glds16(pB[1] + ko, Bn + dB[1]);
        }
      }
      const int go = (((s << 2) | qq) ^ rx) << 3;
      bf16x8 af[4], bf[4];
#pragma unroll
      for (int i = 0; i < 4; i++)
        af[i] = *(const bf16x8*)&Ab[(wm * 64 + i * 16 + r) * TK + go];
#pragma unroll
      for (int j = 0; j < 4; j++)
        bf[j] = *(const bf16x8*)&Bb[(wn * 64 + j * 16 + r) * TK + go];
      __builtin_amdgcn_s_setprio(1);
#pragma unroll
      for (int i = 0; i < 4; i++)
#pragma unroll
        for (int j = 0; j < 4; j++)
          acc[i][j] = __builtin_amdgcn_mfma_f32_16x16x32_bf16(af[i], bf[j], acc[i][j], 0, 0, 0);
      __builtin_amdgcn_s_setprio(0);
    }
    if (t < NKT - 1) {
      if (pf) asm volatile("s_waitcnt vmcnt(6)" ::: "memory");
      else    asm volatile("s_waitcnt vmcnt(0)" ::: "memory");
      __builtin_amdgcn_s_barrier();
      asm volatile("" ::: "memory");
      __builtin_amdgcn_sched_barrier(0);
    }
    cur = (cur == 2) ? 0 : cur + 1;
  }
  const int orow0 = off + m0 + wm * 64 + qq * 4;
#pragma unroll
  for (int j = 0; j < 4; j++) {
    const int n = n0 + wn * 64 + j * 16 + r;
    const float bj = bias[n];
#pragma unroll
    for (int i = 0; i < 4; i++) {
#pragma unroll
      for (int g = 0; g < 4; g++) {
        const int row = orow0 + i * 16 + g;
        Y[(size_t)row * CD + n] = acc[i][j][g] + bj;
      }
    }
  }
}

// out[t] = w0 * Y[s0] + w1 * Y[s1]  (each Y row already includes its expert's bias)
__global__ void combine_kernel(const float* __restrict__ Y, const int* __restrict__ tok_slot,
                               const float* __restrict__ route_w, float* __restrict__ out) {
  const int t = blockIdx.x;
  const int i = threadIdx.x;
  const int s0 = tok_slot[t * 2 + 0], s1 = tok_slot[t * 2 + 1];
  const float w0 = route_w[t * 2 + 0], w1v = route_w[t * 2 + 1];
  const float4 a = ((const float4*)(Y + (size_t)s0 * CD))[i];
  const float4 b = ((const float4*)(Y + (size_t)s1 * CD))[i];
  float4 o;
  o.x = w0 * a.x + w1v * b.x;
  o.y = w0 * a.y + w1v * b.y;
  o.z = w0 * a.z + w1v * b.z;
  o.w = w0 * a.w + w1v * b.w;
  ((float4*)(out + (size_t)t * CD))[i] = o;
}

extern "C" void kernel_launch(void* const* d_in, const int* in_sizes, int n_in,
                              void* d_out, int out_size, void* d_ws, size_t ws_size,
                              hipStream_t stream) {
  const float* x  = (const float*)d_in[0];
  const float* gw = (const float*)d_in[1];
  const float* w1 = (const float*)d_in[2];
  const float* b1 = (const float*)d_in[3];
  const float* w2 = (const float*)d_in[4];
  const float* b2 = (const float*)d_in[5];
  float* out = (float*)d_out;

  char* p = (char*)d_ws;
  size_t o = 0;
  int* meta = (int*)p;                   o = 256;
  int* slot_token = (int*)(p + o);       o += (size_t)MAX_SLOTS * 4;
  int* tok_slot = (int*)(p + o);         o += (size_t)T_TOK * 8;
  int* route_e = (int*)(p + o);          o += (size_t)T_TOK * 8;
  float* route_w = (float*)(p + o);      o += (size_t)T_TOK * 8;
  o = (o + 255) & ~(size_t)255;
  unsigned short* xg  = (unsigned short*)(p + o); o += (size_t)MAX_SLOTS * CD * 2;
  unsigned short* w1b = (unsigned short*)(p + o); o += (size_t)NE * HD * CD * 2;
  unsigned short* w2b = (unsigned short*)(p + o); o += (size_t)NE * CD * HD * 2;
  unsigned short* h   = (unsigned short*)(p + o); o += (size_t)MAX_SLOTS * HD * 2;
  if (ws_size < o) return;  // fail cleanly if workspace too small
  // Y (75.5 MB f32) aliases [xg, w1b) (104.8 MB): both dead once gemm1 completes.
  float* Y = (float*)xg;

  hipMemsetAsync(meta, 0, 256, stream);
  hipMemsetAsync(slot_token, 0xFF, (size_t)MAX_SLOTS * 4, stream);  // -1

  router_kernel<<<T_TOK / 16, 256, 0, stream>>>(x, gw, meta, route_e, route_w);
  offsets_kernel<<<1, 64, 0, stream>>>(meta);
  scatter_kernel<<<T_TOK / 256, 256, 0, stream>>>(route_e, route_w, meta, slot_token, tok_slot);
  gather_kernel<<<MAX_SLOTS, 256, 0, stream>>>(x, slot_token, xg);

  const int n4w = NE * HD * CD / 4;
  cvtw_kernel<<<2 * n4w / 256, 256, 0, stream>>>(w1, w2, w1b, w2b);

  // gemm1: 8 experts x (36 m x 32 n); gemm2: 8 x (36 m x 8 n); inactive m-blocks exit early
  gemm1_kernel<<<NE * MB36 * 32, 512, 0, stream>>>(xg, w1b, b1, h, meta);
  gemm2_kernel<<<NE * MB36 * 8, 512, 0, stream>>>(h, w2b, b2, meta, Y);
  combine_kernel<<<T_TOK, 256, 0, stream>>>(Y, tok_slot, route_w, out);
}

// Round 5
// 713.482 us; speedup vs baseline: 1.4134x; 1.3826x over previous
//
#include <hip/hip_runtime.h>
#include <math.h>

#define T_TOK 8192
#define CD 1024
#define HD 4096
#define NE 8
#define MAX_SLOTS 18432   // 16384 + 8*255 pad, rounded up

#define BM 128
#define BN 128
#define BK 64
#define MSLOTS 64         // max m-blocks per expert: 8192 rows / 128
#define G1_NB 32          // HD / BN
#define G2_NB 8           // CD / BN

typedef __bf16 bf16x8 __attribute__((ext_vector_type(8)));
typedef float f32x4 __attribute__((ext_vector_type(4)));

__device__ __forceinline__ unsigned short f2bf(float f) {
  union { float f; unsigned int u; } v; v.f = f;
  unsigned int u = v.u;
  return (unsigned short)((u + 0x7FFFu + ((u >> 16) & 1u)) >> 16);  // RNE
}

__device__ __forceinline__ float gelu_fast(float x) {
  // tanh-form gelu as x * sigmoid(2z)
  float x3 = x * x * x;
  float z = 0.7978845608028654f * (x + 0.044715f * x3);
  float ez = __expf(-2.0f * z);
  return x * __builtin_amdgcn_rcpf(1.0f + ez);
}

__device__ __forceinline__ void glds16(const void* g, void* l) {
  __builtin_amdgcn_global_load_lds((__attribute__((address_space(1))) void*)g,
                                   (__attribute__((address_space(3))) void*)l,
                                   16, 0, 0);
}

// ---------------- router ----------------
__global__ void router_kernel(const float* __restrict__ x, const float* __restrict__ gw,
                              int* __restrict__ meta, int* __restrict__ route_e,
                              float* __restrict__ route_w) {
  __shared__ float4 sgw4[NE * (CD / 4)];  // 32 KB
  __shared__ int hist[NE];
  const int tid = threadIdx.x;
  for (int idx = tid; idx < NE * CD / 4; idx += 256) sgw4[idx] = ((const float4*)gw)[idx];
  if (tid < NE) hist[tid] = 0;
  __syncthreads();
  const int wave = tid >> 6, lane = tid & 63;
  const int t0 = blockIdx.x * 16 + wave * 4;
#pragma unroll
  for (int tt = 0; tt < 4; tt++) {
    const int t = t0 + tt;
    const float4* xr4 = (const float4*)(x + (size_t)t * CD);
    float4 xv[4];
#pragma unroll
    for (int it = 0; it < 4; it++) xv[it] = xr4[it * 64 + lane];
    float acc[NE];
#pragma unroll
    for (int e = 0; e < NE; e++) acc[e] = 0.f;
#pragma unroll
    for (int it = 0; it < 4; it++) {
#pragma unroll
      for (int e = 0; e < NE; e++) {
        float4 g = sgw4[e * 256 + it * 64 + lane];
        acc[e] += xv[it].x * g.x + xv[it].y * g.y + xv[it].z * g.z + xv[it].w * g.w;
      }
    }
#pragma unroll
    for (int e = 0; e < NE; e++) {
      float v = acc[e];
#pragma unroll
      for (int off = 32; off > 0; off >>= 1) v += __shfl_xor(v, off);
      acc[e] = v;
    }
    if (lane == 0) {
      float mx = acc[0];
#pragma unroll
      for (int e = 1; e < NE; e++) mx = fmaxf(mx, acc[e]);
      float p[NE], s = 0.f;
#pragma unroll
      for (int e = 0; e < NE; e++) { p[e] = __expf(acc[e] - mx); s += p[e]; }
      float inv = 1.0f / s;
#pragma unroll
      for (int e = 0; e < NE; e++) p[e] *= inv;
      int i0 = 0;
#pragma unroll
      for (int e = 1; e < NE; e++) if (p[e] > p[i0]) i0 = e;  // strict >: lowest idx on tie
      int i1 = (i0 == 0) ? 1 : 0;
#pragma unroll
      for (int e = 0; e < NE; e++) if (e != i0 && p[e] > p[i1]) i1 = e;
      float den = p[i0] + p[i1] + 1e-8f;
      route_e[t * 2 + 0] = i0; route_e[t * 2 + 1] = i1;
      route_w[t * 2 + 0] = p[i0] / den; route_w[t * 2 + 1] = p[i1] / den;
      atomicAdd(&hist[i0], 1);
      atomicAdd(&hist[i1], 1);
    }
  }
  __syncthreads();
  if (tid < NE && hist[tid] > 0) atomicAdd(&meta[tid], hist[tid]);
}

// meta: [0:8) cnt, [8:16) offs, [16:24) mpad, [24:32) cursor
__global__ void offsets_kernel(int* meta) {
  if (threadIdx.x == 0 && blockIdx.x == 0) {
    int off = 0;
    for (int e = 0; e < NE; e++) {
      int pc = (meta[e] + 255) & ~255;   // pad to 256 rows (multiple of BM=128)
      meta[8 + e] = off;
      meta[16 + e] = pc;
      off += pc;
    }
  }
}

__global__ void scatter_kernel(const int* __restrict__ route_e, const float* __restrict__ route_w,
                               int* __restrict__ meta, int* __restrict__ slot_token,
                               int* __restrict__ tok_slot) {
  __shared__ int hist[NE], base[NE];
  const int tid = threadIdx.x;
  const int t = blockIdx.x * 256 + tid;
  if (tid < NE) hist[tid] = 0;
  __syncthreads();
  int e0 = route_e[t * 2 + 0], e1 = route_e[t * 2 + 1];
  int lr0 = atomicAdd(&hist[e0], 1);
  int lr1 = atomicAdd(&hist[e1], 1);
  __syncthreads();
  if (tid < NE) base[tid] = (hist[tid] > 0) ? atomicAdd(&meta[24 + tid], hist[tid]) : 0;
  __syncthreads();
  int s0 = meta[8 + e0] + base[e0] + lr0;
  int s1 = meta[8 + e1] + base[e1] + lr1;
  slot_token[s0] = t;
  slot_token[s1] = t;
  tok_slot[t * 2 + 0] = s0;
  tok_slot[t * 2 + 1] = s1;
}

__global__ void gather_kernel(const float* __restrict__ x, const int* __restrict__ slot_token,
                              unsigned short* __restrict__ xg) {
  int slot = blockIdx.x;
  int tkn = slot_token[slot];
  int i = threadIdx.x * 4;
  ushort4 o;
  if (tkn < 0) {
    o.x = 0; o.y = 0; o.z = 0; o.w = 0;
  } else {
    const float4 v = *(const float4*)(x + (size_t)tkn * CD + i);
    o.x = f2bf(v.x); o.y = f2bf(v.y); o.z = f2bf(v.z); o.w = f2bf(v.w);
  }
  *(ushort4*)(xg + (size_t)slot * CD + i) = o;
}

// convert both weight tensors in one launch (each NE*HD*CD floats)
__global__ void cvtw_kernel(const float* __restrict__ w1, const float* __restrict__ w2,
                            unsigned short* __restrict__ d1, unsigned short* __restrict__ d2) {
  const int n4 = NE * HD * CD / 4;
  int i = blockIdx.x * 256 + threadIdx.x;
  const float* s; unsigned short* d;
  if (i < n4) { s = w1; d = d1; }
  else        { s = w2; d = d2; i -= n4; }
  const float4 v = *(const float4*)(s + (size_t)i * 4);
  ushort4 o;
  o.x = f2bf(v.x); o.y = f2bf(v.y); o.z = f2bf(v.z); o.w = f2bf(v.w);
  *(ushort4*)(d + (size_t)i * 4) = o;
}

// ======================= GEMM1: h = gelu(x_g @ w1^T + b1), K=CD =======================
// m97 structure: 128x128 tile, 256 threads (4 waves, 2 wm x 2 wn, per-wave 64x64),
// BK=64, 32 KB LDS. __launch_bounds__(256,4): 60 VGPR + 64 AGPR = 124 <= 128 regs
// -> 4 blocks/CU (vs 3 at R1), more TLP to cover the per-barrier vmcnt drain.
// Single-buffer 2-barrier K-loop, XOR-swizzled 16B granules. Expert pinned to XCD.
__global__ __launch_bounds__(256, 4)
void gemm1_kernel(const unsigned short* __restrict__ Ag,   // x_g [MAX_SLOTS][CD]
                  const unsigned short* __restrict__ W1,   // bf16 w1 [NE][HD][CD]
                  const float* __restrict__ b1,            // [NE][HD]
                  unsigned short* __restrict__ Hout,       // h [MAX_SLOTS][HD]
                  const int* __restrict__ meta) {
  const int gid = blockIdx.x;
  const int e = gid & 7;
  const int rr = gid >> 3;                 // [0, 2048): 64 m x 32 n
  const int sup = rr >> 4;                 // [0,128): 16 msup x 8 nsup, msup fastest
  const int mi = rr & 3, ni = (rr >> 2) & 3;
  const int m_idx = (sup & 15) * 4 + mi;
  const int n_idx = (sup >> 4) * 4 + ni;
  const int mpad = meta[16 + e];
  const int m0 = m_idx * BM;
  if (m0 >= mpad) return;
  const int n0 = n_idx * BN;
  const int off = meta[8 + e];
  const unsigned short* A = Ag + (size_t)(off + m0) * CD;
  const unsigned short* B = W1 + (size_t)e * (HD * CD) + (size_t)n0 * CD;
  const float* bias = b1 + (size_t)e * HD;

  __shared__ unsigned short As[BM * BK];   // 16 KB
  __shared__ unsigned short Bs[BN * BK];   // 16 KB
  const int tid = threadIdx.x;
  const int lane = tid & 63, wave = tid >> 6;
  const int wm = wave >> 1, wn = wave & 1;
  const int r = lane & 15, qq = lane >> 4;
  const int lr = lane >> 3;
  const int gc = (lane & 7) ^ lr;
  const int rx = r & 7;

  f32x4 acc[4][4];
#pragma unroll
  for (int i = 0; i < 4; i++)
#pragma unroll
    for (int j = 0; j < 4; j++) acc[i][j] = 0.f;

  for (int kt = 0; kt < CD / BK; kt++) {
#pragma unroll
    for (int c = 0; c < 4; c++) {
      const int rowb = wave * 32 + c * 8;
      glds16(A + (size_t)(rowb + lr) * CD + kt * BK + gc * 8, &As[rowb * BK]);
      glds16(B + (size_t)(rowb + lr) * CD + kt * BK + gc * 8, &Bs[rowb * BK]);
    }
    __syncthreads();
#pragma unroll
    for (int s = 0; s < 2; s++) {
      const int go = (((s << 2) | qq) ^ rx) << 3;
      bf16x8 af[4], bfr[4];
#pragma unroll
      for (int i = 0; i < 4; i++)
        af[i] = *(const bf16x8*)&As[(wm * 64 + i * 16 + r) * BK + go];
#pragma unroll
      for (int j = 0; j < 4; j++)
        bfr[j] = *(const bf16x8*)&Bs[(wn * 64 + j * 16 + r) * BK + go];
#pragma unroll
      for (int i = 0; i < 4; i++)
#pragma unroll
        for (int j = 0; j < 4; j++)
          acc[i][j] = __builtin_amdgcn_mfma_f32_16x16x32_bf16(af[i], bfr[j], acc[i][j], 0, 0, 0);
    }
    __syncthreads();
  }
  // epilogue: C/D col = lane&15 (-> n), row = quad*4 + reg (-> m)
#pragma unroll
  for (int j = 0; j < 4; j++) {
    int n = n0 + wn * 64 + j * 16 + r;
    float bj = bias[n];
#pragma unroll
    for (int i = 0; i < 4; i++) {
#pragma unroll
      for (int g = 0; g < 4; g++) {
        int ml = wm * 64 + i * 16 + qq * 4 + g;
        Hout[(size_t)(off + m0 + ml) * HD + n] = f2bf(gelu_fast(acc[i][j][g] + bj));
      }
    }
  }
}

// ========== GEMM2: Y[slot] = h @ w2^T + b2, K=HD. Plain f32 stores (no atomics). ==========
__global__ __launch_bounds__(256, 4)
void gemm2_kernel(const unsigned short* __restrict__ Hin,  // h [MAX_SLOTS][HD]
                  const unsigned short* __restrict__ W2,   // bf16 w2 [NE][CD][HD]
                  const float* __restrict__ b2,            // [NE][CD]
                  const int* __restrict__ meta,
                  float* __restrict__ Y) {                 // [MAX_SLOTS][CD] f32
  const int gid = blockIdx.x;
  const int e = gid & 7;
  const int rr = gid >> 3;                 // [0, 512): 64 m x 8 n
  const int sup = rr >> 4;                 // [0,32): 16 msup x 2 nsup, msup fastest
  const int mi = rr & 3, ni = (rr >> 2) & 3;
  const int m_idx = (sup & 15) * 4 + mi;
  const int n_idx = (sup >> 4) * 4 + ni;
  const int mpad = meta[16 + e];
  const int m0 = m_idx * BM;
  if (m0 >= mpad) return;
  const int n0 = n_idx * BN;
  const int off = meta[8 + e];
  const unsigned short* A = Hin + (size_t)(off + m0) * HD;
  const unsigned short* B = W2 + (size_t)e * (CD * HD) + (size_t)n0 * HD;
  const float* bias = b2 + (size_t)e * CD;

  __shared__ unsigned short As[BM * BK];
  __shared__ unsigned short Bs[BN * BK];
  const int tid = threadIdx.x;
  const int lane = tid & 63, wave = tid >> 6;
  const int wm = wave >> 1, wn = wave & 1;
  const int r = lane & 15, qq = lane >> 4;
  const int lr = lane >> 3;
  const int gc = (lane & 7) ^ lr;
  const int rx = r & 7;

  f32x4 acc[4][4];
#pragma unroll
  for (int i = 0; i < 4; i++)
#pragma unroll
    for (int j = 0; j < 4; j++) acc[i][j] = 0.f;

  for (int kt = 0; kt < HD / BK; kt++) {
#pragma unroll
    for (int c = 0; c < 4; c++) {
      const int rowb = wave * 32 + c * 8;
      glds16(A + (size_t)(rowb + lr) * HD + kt * BK + gc * 8, &As[rowb * BK]);
      glds16(B + (size_t)(rowb + lr) * HD + kt * BK + gc * 8, &Bs[rowb * BK]);
    }
    __syncthreads();
#pragma unroll
    for (int s = 0; s < 2; s++) {
      const int go = (((s << 2) | qq) ^ rx) << 3;
      bf16x8 af[4], bfr[4];
#pragma unroll
      for (int i = 0; i < 4; i++)
        af[i] = *(const bf16x8*)&As[(wm * 64 + i * 16 + r) * BK + go];
#pragma unroll
      for (int j = 0; j < 4; j++)
        bfr[j] = *(const bf16x8*)&Bs[(wn * 64 + j * 16 + r) * BK + go];
#pragma unroll
      for (int i = 0; i < 4; i++)
#pragma unroll
        for (int j = 0; j < 4; j++)
          acc[i][j] = __builtin_amdgcn_mfma_f32_16x16x32_bf16(af[i], bfr[j], acc[i][j], 0, 0, 0);
    }
    __syncthreads();
  }
#pragma unroll
  for (int j = 0; j < 4; j++) {
    int n = n0 + wn * 64 + j * 16 + r;
    float bj = bias[n];
#pragma unroll
    for (int i = 0; i < 4; i++) {
#pragma unroll
      for (int g = 0; g < 4; g++) {
        int ml = wm * 64 + i * 16 + qq * 4 + g;
        Y[(size_t)(off + m0 + ml) * CD + n] = acc[i][j][g] + bj;
      }
    }
  }
}

// out[t] = w0 * Y[s0] + w1 * Y[s1]  (each Y row already includes its expert's bias)
__global__ void combine_kernel(const float* __restrict__ Y, const int* __restrict__ tok_slot,
                               const float* __restrict__ route_w, float* __restrict__ out) {
  const int t = blockIdx.x;
  const int i = threadIdx.x;
  const int s0 = tok_slot[t * 2 + 0], s1 = tok_slot[t * 2 + 1];
  const float w0 = route_w[t * 2 + 0], w1v = route_w[t * 2 + 1];
  const float4 a = ((const float4*)(Y + (size_t)s0 * CD))[i];
  const float4 b = ((const float4*)(Y + (size_t)s1 * CD))[i];
  float4 o;
  o.x = w0 * a.x + w1v * b.x;
  o.y = w0 * a.y + w1v * b.y;
  o.z = w0 * a.z + w1v * b.z;
  o.w = w0 * a.w + w1v * b.w;
  ((float4*)(out + (size_t)t * CD))[i] = o;
}

extern "C" void kernel_launch(void* const* d_in, const int* in_sizes, int n_in,
                              void* d_out, int out_size, void* d_ws, size_t ws_size,
                              hipStream_t stream) {
  const float* x  = (const float*)d_in[0];
  const float* gw = (const float*)d_in[1];
  const float* w1 = (const float*)d_in[2];
  const float* b1 = (const float*)d_in[3];
  const float* w2 = (const float*)d_in[4];
  const float* b2 = (const float*)d_in[5];
  float* out = (float*)d_out;

  char* p = (char*)d_ws;
  size_t o = 0;
  int* meta = (int*)p;                   o = 256;
  int* slot_token = (int*)(p + o);       o += (size_t)MAX_SLOTS * 4;
  int* tok_slot = (int*)(p + o);         o += (size_t)T_TOK * 8;
  int* route_e = (int*)(p + o);          o += (size_t)T_TOK * 8;
  float* route_w = (float*)(p + o);      o += (size_t)T_TOK * 8;
  o = (o + 255) & ~(size_t)255;
  unsigned short* xg  = (unsigned short*)(p + o); o += (size_t)MAX_SLOTS * CD * 2;
  unsigned short* w1b = (unsigned short*)(p + o); o += (size_t)NE * HD * CD * 2;
  unsigned short* w2b = (unsigned short*)(p + o); o += (size_t)NE * CD * HD * 2;
  unsigned short* h   = (unsigned short*)(p + o); o += (size_t)MAX_SLOTS * HD * 2;
  if (ws_size < o) return;  // fail cleanly if workspace too small
  // Y (75.5 MB f32) aliases [xg, w1b) (104.8 MB): both are dead once gemm1 completes,
  // and gemm2/combine run strictly after gemm1 on this stream.
  float* Y = (float*)xg;

  hipMemsetAsync(meta, 0, 256, stream);
  hipMemsetAsync(slot_token, 0xFF, (size_t)MAX_SLOTS * 4, stream);  // -1

  router_kernel<<<T_TOK / 16, 256, 0, stream>>>(x, gw, meta, route_e, route_w);
  offsets_kernel<<<1, 64, 0, stream>>>(meta);
  scatter_kernel<<<T_TOK / 256, 256, 0, stream>>>(route_e, route_w, meta, slot_token, tok_slot);
  gather_kernel<<<MAX_SLOTS, 256, 0, stream>>>(x, slot_token, xg);

  const int n4w = NE * HD * CD / 4;
  cvtw_kernel<<<2 * n4w / 256, 256, 0, stream>>>(w1, w2, w1b, w2b);

  // gemm1: 8 experts x (64 m x 32 n); gemm2: 8 x (64 m x 8 n); inactive m-blocks early-return
  gemm1_kernel<<<NE * MSLOTS * G1_NB, 256, 0, stream>>>(xg, w1b, b1, h, meta);
  gemm2_kernel<<<NE * MSLOTS * G2_NB, 256, 0, stream>>>(h, w2b, b2, meta, Y);
  combine_kernel<<<T_TOK, 256, 0, stream>>>(Y, tok_slot, route_w, out);
}